// Round 23
// baseline (46.128 us; speedup 1.0000x reference)
//
#include <hip/hip_runtime.h>
#include <hip/hip_fp16.h>

// SSIM loss — round 23: fused h-phase (r19 retry with r20 operand-swap +
// r22 asm-blob loads). No sIn, no prep phase, one fewer barrier.
// 256 thr / 4 waves; wave = col-chunk ct. Per rt in {0,16,26}: asm-blob
// 4x global_load_dwordx4 (single latency exposure), f16 convert, 4
// q-fragments in-register, 4 operand-swapped MFMAs (D rows = image rows
// -> b64 col-major sV stores). v-phase: windows {0,12}, rows 42/43 zeroed,
// 2xb64 reads, 2 positions/wave. LDS 22.9KB -> 7 blocks/CU.

#define IMGH 512
#define IMGW 512
#define TW 64
#define TH 32
#define GX 8
#define GY 16
#define GZ 48
#define NBLOCKS (GX * GY * GZ)   // 6144
#define NPIX (16 * 3 * 512 * 512)
#define C1F 1.0e-4f
#define C2F 9.0e-4f

#define VSTRIDE 44         // halfs/col (88B); rows 42,43 zeroed for window 12
#define VPLANE (64 * VSTRIDE)
#define WBASE 34

// Gaussian weights, sigma=1.5, ws=11 (validated r1-r22).
#define W0 0.0010283818f
#define W1 0.0075987503f
#define W2 0.0360007547f
#define W3 0.1093606960f
#define W4 0.2130055367f
#define W5 0.2660117184f

typedef _Float16 half8v __attribute__((ext_vector_type(8)));
typedef float f32x4 __attribute__((ext_vector_type(4)));
union H8 { half8v v; __half2 h2[4]; float4 f4; unsigned u[4]; };

static __device__ __forceinline__ __half2 pkrtz(float a, float b) {
    auto r = __builtin_amdgcn_cvt_pkrtz(a, b);   // __fp16 ext_vector(2)
    return *reinterpret_cast<__half2*>(&r);
}
static __device__ __forceinline__ float wval(int i) {
    const float W[11] = {W0, W1, W2, W3, W4, W5, W4, W3, W2, W1, W0};
    float w = 0.f;
#pragma unroll
    for (int j = 0; j < 11; ++j) w = (i == WBASE + j) ? W[j] : w;
    return w;
}

__global__ __launch_bounds__(256, 6)
void ssim_tile(const float* __restrict__ img1, const float* __restrict__ img2,
               float* __restrict__ partials) {
    __shared__ _Float16 sWext[96];          // [WBASE..WBASE+10] = W[0..10]
    __shared__ _Float16 sV[4 * VPLANE];     // 22,528 B : col-major, 44 rows
    __shared__ float wsum[4];

    const int tid  = threadIdx.x;
    const int lane = tid & 63;
    const int wv   = tid >> 6;              // 0..3 = ct
    const int lr = lane & 15;
    const int kc = lane >> 4;
    const int r0 = blockIdx.y * TH;
    const int c0 = blockIdx.x * TW;
    const size_t pbase = (size_t)blockIdx.z * (IMGH * IMGW);
    const float* a0 = img1 + pbase;
    const float* b0 = img2 + pbase;
    const bool fast = (blockIdx.x >= 1) & (blockIdx.x <= GX - 2) &
                      (blockIdx.y >= 1) & (blockIdx.y <= GY - 2);

    // ---- weight table + zero sV rows 42,43 ----
    if (tid < 96) sWext[tid] = (_Float16)wval(tid);
    {
        const int q = tid >> 6, col = tid & 63;
        *reinterpret_cast<unsigned*>(&sV[q * VPLANE + col * VSTRIDE + 42]) = 0u;
    }
    __syncthreads();

    // ---- weight fragments (m89 layout: M/N=lane&15, K=(lane>>4)*8+e) ----
    half8v Wh, Av0, Av1;
    {
        const int bi = (kc << 3) - lr + WBASE;
#pragma unroll
        for (int e = 0; e < 8; ++e) Wh[e]  = sWext[bi - 3 + e];   // W[k-n-3]
#pragma unroll
        for (int e = 0; e < 8; ++e) Av0[e] = sWext[bi + e];       // W[k-m]
#pragma unroll
        for (int e = 0; e < 8; ++e) Av1[e] = sWext[bi - 4 + e];   // W[k-m-4]
    }

    // ---- fused h-phase: wave = ct; rt in {0,16,26}; direct global loads ----
    {
        const int ct = wv;
        const int gcb = c0 - 8 + 16 * ct + (kc << 3);   // 8 f32: gcb..gcb+7
#pragma unroll
        for (int rt = 0; rt < 3; ++rt) {
            const int rb = (rt == 0) ? 0 : (rt == 1 ? 16 : 26);
            const int row = rb + lr;                    // image h-row (M dim)
            const int gr = r0 - 5 + row;
            f32x4 va1, va2, vb1, vb2;
            if (fast) {
                const float* pa = a0 + (size_t)gr * IMGW + gcb;
                const float* pb = b0 + (size_t)gr * IMGW + gcb;
                asm volatile(
                    "global_load_dwordx4 %0, %4, off\n\t"
                    "global_load_dwordx4 %1, %4, off offset:16\n\t"
                    "global_load_dwordx4 %2, %5, off\n\t"
                    "global_load_dwordx4 %3, %5, off offset:16\n\t"
                    "s_waitcnt vmcnt(0)"
                    : "=&v"(va1), "=&v"(va2), "=&v"(vb1), "=&v"(vb2)
                    : "v"(pa), "v"(pb)
                    : "memory");
            } else {
                const f32x4 z = (f32x4){0.f, 0.f, 0.f, 0.f};
                const bool okr = (unsigned)gr < IMGH;
                const bool ok1 = okr & ((unsigned)gcb < IMGW);
                const bool ok2 = okr & ((unsigned)(gcb + 4) < IMGW);
                const int grc = okr ? gr : 0;
                const int g1 = ok1 ? gcb : 0;
                const int g2 = ok2 ? gcb + 4 : 4;
                const float* pa = a0 + (size_t)grc * IMGW;
                const float* pb = b0 + (size_t)grc * IMGW;
                f32x4 t;
                t = *reinterpret_cast<const f32x4*>(pa + g1); va1 = ok1 ? t : z;
                t = *reinterpret_cast<const f32x4*>(pa + g2); va2 = ok2 ? t : z;
                t = *reinterpret_cast<const f32x4*>(pb + g1); vb1 = ok1 ? t : z;
                t = *reinterpret_cast<const f32x4*>(pb + g2); vb2 = ok2 ? t : z;
            }
            H8 ha, hb, fq, fc;
            ha.h2[0] = pkrtz(va1[0], va1[1]); ha.h2[1] = pkrtz(va1[2], va1[3]);
            ha.h2[2] = pkrtz(va2[0], va2[1]); ha.h2[3] = pkrtz(va2[2], va2[3]);
            hb.h2[0] = pkrtz(vb1[0], vb1[1]); hb.h2[1] = pkrtz(vb1[2], vb1[3]);
            hb.h2[2] = pkrtz(vb2[0], vb2[1]); hb.h2[3] = pkrtz(vb2[2], vb2[3]);
#pragma unroll
            for (int t = 0; t < 4; ++t) {
                fq.h2[t] = __hfma2(ha.h2[t], ha.h2[t],
                                   __hmul2(hb.h2[t], hb.h2[t]));
                fc.h2[t] = __hmul2(ha.h2[t], hb.h2[t]);
            }
            f32x4 d0 = {0.f, 0.f, 0.f, 0.f}, d1 = d0, d2 = d0, d3 = d0;
            d0 = __builtin_amdgcn_mfma_f32_16x16x32_f16(ha.v, Wh, d0, 0, 0, 0);
            d1 = __builtin_amdgcn_mfma_f32_16x16x32_f16(hb.v, Wh, d1, 0, 0, 0);
            d2 = __builtin_amdgcn_mfma_f32_16x16x32_f16(fq.v, Wh, d2, 0, 0, 0);
            d3 = __builtin_amdgcn_mfma_f32_16x16x32_f16(fc.v, Wh, d3, 0, 0, 0);
            // D: lane = out-col 16ct+lr (N), rows rb+4kc+j (M) -> col-major
            const int vb = (16 * ct + lr) * VSTRIDE + rb + (kc << 2);
            uint2 s[4];
            __half2 h;
            h = pkrtz(d0[0], d0[1]); s[0].x = *reinterpret_cast<unsigned*>(&h);
            h = pkrtz(d0[2], d0[3]); s[0].y = *reinterpret_cast<unsigned*>(&h);
            h = pkrtz(d1[0], d1[1]); s[1].x = *reinterpret_cast<unsigned*>(&h);
            h = pkrtz(d1[2], d1[3]); s[1].y = *reinterpret_cast<unsigned*>(&h);
            h = pkrtz(d2[0], d2[1]); s[2].x = *reinterpret_cast<unsigned*>(&h);
            h = pkrtz(d2[2], d2[3]); s[2].y = *reinterpret_cast<unsigned*>(&h);
            h = pkrtz(d3[0], d3[1]); s[3].x = *reinterpret_cast<unsigned*>(&h);
            h = pkrtz(d3[2], d3[3]); s[3].y = *reinterpret_cast<unsigned*>(&h);
            if (rt < 2) {
#pragma unroll
                for (int q = 0; q < 4; ++q)
                    *reinterpret_cast<uint2*>(&sV[q * VPLANE + vb]) = s[q];
            } else {     // rb=26: 4B-aligned only
#pragma unroll
                for (int q = 0; q < 4; ++q) {
                    unsigned* p = reinterpret_cast<unsigned*>(&sV[q * VPLANE + vb]);
                    p[0] = s[q].x; p[1] = s[q].y;
                }
            }
        }
    }
    __syncthreads();

    // ---- v-phase: wave wv = ct2; rt2 = 0,1; 2xb64 reads; SSIM ----
    float lsum = 0.f;
#pragma unroll
    for (int rt2 = 0; rt2 < 2; ++rt2) {
        const int w0 = rt2 ? 12 : 0;
        const half8v Avx = rt2 ? Av1 : Av0;
        const int vbase = (16 * wv + lr) * VSTRIDE + w0 + (kc << 3);
        auto vread = [&](int q) -> half8v {
            const _Float16* p = &sV[q * VPLANE + vbase];
            H8 c;
            *reinterpret_cast<uint2*>(&c.u[0]) =
                *reinterpret_cast<const uint2*>(p);
            *reinterpret_cast<uint2*>(&c.u[2]) =
                *reinterpret_cast<const uint2*>(p + 4);
            return c.v;
        };
        f32x4 d0 = {0.f, 0.f, 0.f, 0.f}, d1 = d0, d2 = d0, d3 = d0;
        d0 = __builtin_amdgcn_mfma_f32_16x16x32_f16(Avx, vread(0), d0, 0, 0, 0);
        d1 = __builtin_amdgcn_mfma_f32_16x16x32_f16(Avx, vread(1), d1, 0, 0, 0);
        d2 = __builtin_amdgcn_mfma_f32_16x16x32_f16(Avx, vread(2), d2, 0, 0, 0);
        d3 = __builtin_amdgcn_mfma_f32_16x16x32_f16(Avx, vread(3), d3, 0, 0, 0);
#pragma unroll
        for (int r = 0; r < 4; ++r) {
            const float mu1 = d0[r], mu2 = d1[r], S = d2[r], eab = d3[r];
            const float mu11 = mu1 * mu1, mu22 = mu2 * mu2, mu12 = mu1 * mu2;
            const float s12 = eab - mu12;
            const float num = (2.f * mu12 + C1F) * (2.f * s12 + C2F);
            const float den = (mu11 + mu22 + C1F) * ((S - mu11 - mu22) + C2F);
            lsum += num * __builtin_amdgcn_rcpf(den);
        }
    }

    // ---- deterministic block reduction (4 waves) ----
#pragma unroll
    for (int off = 32; off > 0; off >>= 1) lsum += __shfl_down(lsum, off, 64);
    if (lane == 0) wsum[wv] = lsum;
    __syncthreads();
    if (tid == 0) {
        float t = wsum[0] + wsum[1] + wsum[2] + wsum[3];
        partials[((size_t)blockIdx.z * GY + blockIdx.y) * GX + blockIdx.x] = t;
    }
}

__global__ __launch_bounds__(1024)
void ssim_reduce(const float* __restrict__ partials, float* __restrict__ out, int n) {
    __shared__ float lds[1024];
    float s = 0.f;
    for (int i = threadIdx.x; i < n; i += 1024) s += partials[i];
    lds[threadIdx.x] = s;
    __syncthreads();
    for (int off = 512; off > 0; off >>= 1) {
        if ((int)threadIdx.x < off) lds[threadIdx.x] += lds[threadIdx.x + off];
        __syncthreads();
    }
    if (threadIdx.x == 0) out[0] = 1.f - lds[0] / (float)NPIX;
}

extern "C" void kernel_launch(void* const* d_in, const int* in_sizes, int n_in,
                              void* d_out, int out_size, void* d_ws, size_t ws_size,
                              hipStream_t stream) {
    const float* img1 = (const float*)d_in[0];
    const float* img2 = (const float*)d_in[1];
    float* out = (float*)d_out;
    float* partials = (float*)d_ws;

    dim3 grid(GX, GY, GZ);
    ssim_tile<<<grid, 256, 0, stream>>>(img1, img2, partials);
    ssim_reduce<<<1, 1024, 0, stream>>>(partials, out, NBLOCKS);
}

// Round 24
// 39.504 us; speedup vs baseline: 1.1677x; 1.1677x over previous
//
#include <hip/hip_runtime.h>
#include <hip/hip_fp16.h>

// SSIM loss — round 24: r22 core + 4-tile z-loop with cross-tile load pipeline.
// Each block does 4 z-plane tiles (grid 1536). Prep loads for tile t+1 are
// ISSUED (asm, no wait) right after barrier A of tile t and fly under
// h-phase(t)+v-phase(t); the wait is a separate asm with "+v" reg constraints
// (data-dep ties converts to the wait). 2 barriers/tile; hazard order:
// convert(t+1) after barrier B(t) [all h(t) sIn-reads done], h(t+1) after
// barrier A(t+1) [all v(t) sV-reads done]. Boundary blocks: unpipelined
// guarded loads. Core per tile = r22: operand-swapped h-MFMA (b64 col-major
// stores), q-pair split, v windows {0,12}. 512 thr, LDS 37.9KB, 4 blk/CU.

#define IMGH 512
#define IMGW 512
#define TW 64
#define TH 32
#define GX 8
#define GY 16
#define GZT 12             // grid.z ; each block does 4 z-planes
#define NBLOCKS (GX * GY * GZT)  // 1536
#define NPIX (16 * 3 * 512 * 512)
#define C1F 1.0e-4f
#define C2F 9.0e-4f

#define INSTRIDE 88        // halfs/row (176B, b128-aligned reads)
#define INPLANE (42 * INSTRIDE)
#define VSTRIDE 44         // halfs/col (88B); rows 42,43 zeroed for window 12
#define VPLANE (64 * VSTRIDE)
#define WBASE 34

// Gaussian weights, sigma=1.5, ws=11 (validated r1-r23).
#define W0 0.0010283818f
#define W1 0.0075987503f
#define W2 0.0360007547f
#define W3 0.1093606960f
#define W4 0.2130055367f
#define W5 0.2660117184f

typedef _Float16 half8v __attribute__((ext_vector_type(8)));
typedef float f32x4 __attribute__((ext_vector_type(4)));
union H8 { half8v v; __half2 h2[4]; float4 f4; unsigned u[4]; };

static __device__ __forceinline__ __half2 pkrtz(float a, float b) {
    auto r = __builtin_amdgcn_cvt_pkrtz(a, b);   // __fp16 ext_vector(2)
    return *reinterpret_cast<__half2*>(&r);
}
static __device__ __forceinline__ float wval(int i) {
    const float W[11] = {W0, W1, W2, W3, W4, W5, W4, W3, W2, W1, W0};
    float w = 0.f;
#pragma unroll
    for (int j = 0; j < 11; ++j) w = (i == WBASE + j) ? W[j] : w;
    return w;
}

__global__ __launch_bounds__(512, 6)
void ssim_tile(const float* __restrict__ img1, const float* __restrict__ img2,
               float* __restrict__ partials) {
    __shared__ _Float16 sWext[96];          // [WBASE..WBASE+10] = W[0..10]
    __shared__ _Float16 sIn[2 * INPLANE];   // 14,784 B : a | b
    __shared__ _Float16 sV[4 * VPLANE];     // 22,528 B : col-major, 44 rows
    __shared__ float wsum[8];

    const int tid  = threadIdx.x;
    const int lane = tid & 63;
    const int wv   = tid >> 6;
    const int lr = lane & 15;
    const int kc = lane >> 4;
    const int r0 = blockIdx.y * TH;
    const int c0 = blockIdx.x * TW;
    const bool fast = (blockIdx.x >= 1) & (blockIdx.x <= GX - 2) &
                      (blockIdx.y >= 1) & (blockIdx.y <= GY - 2);

    // prep item geometry (tid < 420)
    const int prow = (unsigned)tid / 10u;
    const int pch  = tid - prow * 10;
    const int pgr  = r0 - 5 + prow;
    const int pgc  = c0 - 8 + 8 * pch;
    const bool pok = (unsigned)pgr < IMGH && (unsigned)pgc < IMGW;
    const size_t goff = (size_t)pgr * IMGW + pgc;

    // per-tile image base (4 consecutive z-planes)
    const float* pa4[4];
    const float* pb4[4];
#pragma unroll
    for (int t = 0; t < 4; ++t) {
        const size_t pbase = ((size_t)blockIdx.z * 4 + t) * (IMGH * IMGW);
        pa4[t] = img1 + pbase;
        pb4[t] = img2 + pbase;
    }

    // aux: weight table + zero sV rows 42,43 (wave 7; prep threads are <420)
    if (tid >= 448) {
        const int t = tid - 448;
        sWext[t] = (_Float16)wval(t);
        if (t < 32) sWext[t + 64] = (_Float16)wval(t + 64);
#pragma unroll
        for (int j = 0; j < 4; ++j) {
            const int w = t + (j << 6);
            const int q = w >> 6, col = w & 63;
            *reinterpret_cast<unsigned*>(&sV[q * VPLANE + col * VSTRIDE + 42]) = 0u;
        }
    }

    f32x4 va1, va2, vb1, vb2;       // in-flight prep load registers
    const bool pipeline = fast && (tid < 420);

    // prologue: issue tile-0 loads
    if (pipeline) {
        const float* pa = pa4[0] + goff;
        const float* pb = pb4[0] + goff;
        asm volatile(
            "global_load_dwordx4 %0, %4, off\n\t"
            "global_load_dwordx4 %1, %4, off offset:16\n\t"
            "global_load_dwordx4 %2, %5, off\n\t"
            "global_load_dwordx4 %3, %5, off offset:16"
            : "=&v"(va1), "=&v"(va2), "=&v"(vb1), "=&v"(vb2)
            : "v"(pa), "v"(pb)
            : "memory");
    }

    half8v Wh, Av0, Av1;
    float lsum = 0.f;

#pragma unroll
    for (int t = 0; t < 4; ++t) {
        // ---- convert + store sIn(t) ----
        if (tid < 420) {
            if (pipeline) {
                asm volatile("s_waitcnt vmcnt(0)"
                             : "+v"(va1), "+v"(va2), "+v"(vb1), "+v"(vb2));
            } else {
                va1 = (f32x4){0.f, 0.f, 0.f, 0.f};
                va2 = vb1 = vb2 = va1;
                if (pok) {
                    const float* pa = pa4[t] + goff;
                    const float* pb = pb4[t] + goff;
                    va1 = *reinterpret_cast<const f32x4*>(pa);
                    va2 = *reinterpret_cast<const f32x4*>(pa + 4);
                    vb1 = *reinterpret_cast<const f32x4*>(pb);
                    vb2 = *reinterpret_cast<const f32x4*>(pb + 4);
                }
            }
            const int off = prow * INSTRIDE + 8 * pch;
            H8 ha, hb;
            ha.h2[0] = pkrtz(va1[0], va1[1]); ha.h2[1] = pkrtz(va1[2], va1[3]);
            ha.h2[2] = pkrtz(va2[0], va2[1]); ha.h2[3] = pkrtz(va2[2], va2[3]);
            hb.h2[0] = pkrtz(vb1[0], vb1[1]); hb.h2[1] = pkrtz(vb1[2], vb1[3]);
            hb.h2[2] = pkrtz(vb2[0], vb2[1]); hb.h2[3] = pkrtz(vb2[2], vb2[3]);
            *reinterpret_cast<float4*>(&sIn[off]) = ha.f4;
            *reinterpret_cast<float4*>(&sIn[INPLANE + off]) = hb.f4;
        }
        __syncthreads();                    // barrier A: sIn ready, v(t-1) done

        // issue loads for tile t+1 (fly under h+v of tile t)
        if (t < 3 && pipeline) {
            const float* pa = pa4[t + 1] + goff;
            const float* pb = pb4[t + 1] + goff;
            asm volatile(
                "global_load_dwordx4 %0, %4, off\n\t"
                "global_load_dwordx4 %1, %4, off offset:16\n\t"
                "global_load_dwordx4 %2, %5, off\n\t"
                "global_load_dwordx4 %3, %5, off offset:16"
                : "=&v"(va1), "=&v"(va2), "=&v"(vb1), "=&v"(vb2)
                : "v"(pa), "v"(pb)
                : "memory");
        }
        if (t == 0) {                       // weight fragments (sWext ready)
            const int bi = (kc << 3) - lr + WBASE;
#pragma unroll
            for (int e = 0; e < 8; ++e) Wh[e]  = sWext[bi - 3 + e];  // W[k-n-3]
#pragma unroll
            for (int e = 0; e < 8; ++e) Av0[e] = sWext[bi + e];      // W[k-m]
#pragma unroll
            for (int e = 0; e < 8; ++e) Av1[e] = sWext[bi - 4 + e];  // W[k-m-4]
        }

        // ---- h-phase: 24 half-positions (rt,ct,qp), 3 per wave ----
        {
            const int ct = (wv >> 1) & 3;
            const int qp = wv & 1;
#pragma unroll
            for (int rt = 0; rt < 3; ++rt) {
                const int rb = (rt == 0) ? 0 : (rt == 1 ? 16 : 26);
                const int base = (rb + lr) * INSTRIDE + 16 * ct + (kc << 3);
                H8 fa, fb;
                fa.f4 = *reinterpret_cast<const float4*>(&sIn[base]);
                fb.f4 = *reinterpret_cast<const float4*>(&sIn[INPLANE + base]);
                H8 f0, f1;
                if (qp == 0) {
                    f0 = fa; f1 = fb;
                } else {
#pragma unroll
                    for (int u = 0; u < 4; ++u) {
                        f0.h2[u] = __hfma2(fa.h2[u], fa.h2[u],
                                           __hmul2(fb.h2[u], fb.h2[u]));
                        f1.h2[u] = __hmul2(fa.h2[u], fb.h2[u]);
                    }
                }
                f32x4 d0 = {0.f, 0.f, 0.f, 0.f}, d1 = d0;
                d0 = __builtin_amdgcn_mfma_f32_16x16x32_f16(f0.v, Wh, d0, 0, 0, 0);
                d1 = __builtin_amdgcn_mfma_f32_16x16x32_f16(f1.v, Wh, d1, 0, 0, 0);
                const int p0 = qp * 2, p1 = qp * 2 + 1;
                const int vb = (16 * ct + lr) * VSTRIDE + rb + (kc << 2);
                uint2 s0, s1;
                __half2 h;
                h = pkrtz(d0[0], d0[1]); s0.x = *reinterpret_cast<unsigned*>(&h);
                h = pkrtz(d0[2], d0[3]); s0.y = *reinterpret_cast<unsigned*>(&h);
                h = pkrtz(d1[0], d1[1]); s1.x = *reinterpret_cast<unsigned*>(&h);
                h = pkrtz(d1[2], d1[3]); s1.y = *reinterpret_cast<unsigned*>(&h);
                if (rt < 2) {
                    *reinterpret_cast<uint2*>(&sV[p0 * VPLANE + vb]) = s0;
                    *reinterpret_cast<uint2*>(&sV[p1 * VPLANE + vb]) = s1;
                } else {   // rb=26: 4B-aligned only
                    unsigned* q0 = reinterpret_cast<unsigned*>(&sV[p0 * VPLANE + vb]);
                    unsigned* q1 = reinterpret_cast<unsigned*>(&sV[p1 * VPLANE + vb]);
                    q0[0] = s0.x; q0[1] = s0.y;
                    q1[0] = s1.x; q1[1] = s1.y;
                }
            }
        }
        __syncthreads();                    // barrier B: sV ready, sIn free

        // ---- v-phase: ct2 = wv&3, rt2 = wv>>2; 2xb64 reads; SSIM ----
        {
            const int ct2 = wv & 3;
            const int rt2 = wv >> 2;
            const int w0 = rt2 ? 12 : 0;
            const half8v Avx = rt2 ? Av1 : Av0;
            const int vbase = (16 * ct2 + lr) * VSTRIDE + w0 + (kc << 3);
            auto vread = [&](int q) -> half8v {
                const _Float16* p = &sV[q * VPLANE + vbase];
                H8 c;
                *reinterpret_cast<uint2*>(&c.u[0]) =
                    *reinterpret_cast<const uint2*>(p);
                *reinterpret_cast<uint2*>(&c.u[2]) =
                    *reinterpret_cast<const uint2*>(p + 4);
                return c.v;
            };
            f32x4 d0 = {0.f, 0.f, 0.f, 0.f}, d1 = d0, d2 = d0, d3 = d0;
            d0 = __builtin_amdgcn_mfma_f32_16x16x32_f16(Avx, vread(0), d0, 0, 0, 0);
            d1 = __builtin_amdgcn_mfma_f32_16x16x32_f16(Avx, vread(1), d1, 0, 0, 0);
            d2 = __builtin_amdgcn_mfma_f32_16x16x32_f16(Avx, vread(2), d2, 0, 0, 0);
            d3 = __builtin_amdgcn_mfma_f32_16x16x32_f16(Avx, vread(3), d3, 0, 0, 0);
#pragma unroll
            for (int r = 0; r < 4; ++r) {
                const float mu1 = d0[r], mu2 = d1[r], S = d2[r], eab = d3[r];
                const float mu11 = mu1 * mu1, mu22 = mu2 * mu2, mu12 = mu1 * mu2;
                const float s12 = eab - mu12;
                const float num = (2.f * mu12 + C1F) * (2.f * s12 + C2F);
                const float den = (mu11 + mu22 + C1F) * ((S - mu11 - mu22) + C2F);
                lsum += num * __builtin_amdgcn_rcpf(den);
            }
        }
    }

    // ---- deterministic block reduction (8 waves) ----
#pragma unroll
    for (int off = 32; off > 0; off >>= 1) lsum += __shfl_down(lsum, off, 64);
    if (lane == 0) wsum[wv] = lsum;
    __syncthreads();
    if (tid == 0) {
        float t = 0.f;
#pragma unroll
        for (int w = 0; w < 8; ++w) t += wsum[w];
        partials[((size_t)blockIdx.z * GY + blockIdx.y) * GX + blockIdx.x] = t;
    }
}

__global__ __launch_bounds__(1024)
void ssim_reduce(const float* __restrict__ partials, float* __restrict__ out, int n) {
    __shared__ float lds[1024];
    float s = 0.f;
    for (int i = threadIdx.x; i < n; i += 1024) s += partials[i];
    lds[threadIdx.x] = s;
    __syncthreads();
    for (int off = 512; off > 0; off >>= 1) {
        if ((int)threadIdx.x < off) lds[threadIdx.x] += lds[threadIdx.x + off];
        __syncthreads();
    }
    if (threadIdx.x == 0) out[0] = 1.f - lds[0] / (float)NPIX;
}

extern "C" void kernel_launch(void* const* d_in, const int* in_sizes, int n_in,
                              void* d_out, int out_size, void* d_ws, size_t ws_size,
                              hipStream_t stream) {
    const float* img1 = (const float*)d_in[0];
    const float* img2 = (const float*)d_in[1];
    float* out = (float*)d_out;
    float* partials = (float*)d_ws;

    dim3 grid(GX, GY, GZT);
    ssim_tile<<<grid, 512, 0, stream>>>(img1, img2, partials);
    ssim_reduce<<<1, 1024, 0, stream>>>(partials, out, NBLOCKS);
}

// Round 25
// 37.841 us; speedup vs baseline: 1.2190x; 1.0439x over previous
//
#include <hip/hip_runtime.h>
#include <hip/hip_fp16.h>

// SSIM loss — round 25: r24 pipeline + exact block-packing.
// LDS 37.9KB -> exactly 4 blocks/CU = 1024 concurrent slots. r24's grid
// 1536 = 1.5x slots -> one full + one HALF-EMPTY round (2xT4 vs ideal
// 1.5xT4). Fix: 3 tiles/block, grid 8x16x16 = 2048 = exactly 2.0x slots
// -> two perfectly full rounds. Per-tile core + cross-tile load pipeline
// identical to r24 (pipelined per-tile = 4.94us vs 6.65 unpipelined).

#define IMGH 512
#define IMGW 512
#define TW 64
#define TH 32
#define GX 8
#define GY 16
#define GZT 16             // grid.z ; each block does 3 z-planes (48 total)
#define NBLOCKS (GX * GY * GZT)  // 2048
#define NPIX (16 * 3 * 512 * 512)
#define C1F 1.0e-4f
#define C2F 9.0e-4f

#define INSTRIDE 88        // halfs/row (176B, b128-aligned reads)
#define INPLANE (42 * INSTRIDE)
#define VSTRIDE 44         // halfs/col (88B); rows 42,43 zeroed for window 12
#define VPLANE (64 * VSTRIDE)
#define WBASE 34

// Gaussian weights, sigma=1.5, ws=11 (validated r1-r24).
#define W0 0.0010283818f
#define W1 0.0075987503f
#define W2 0.0360007547f
#define W3 0.1093606960f
#define W4 0.2130055367f
#define W5 0.2660117184f

typedef _Float16 half8v __attribute__((ext_vector_type(8)));
typedef float f32x4 __attribute__((ext_vector_type(4)));
union H8 { half8v v; __half2 h2[4]; float4 f4; unsigned u[4]; };

static __device__ __forceinline__ __half2 pkrtz(float a, float b) {
    auto r = __builtin_amdgcn_cvt_pkrtz(a, b);   // __fp16 ext_vector(2)
    return *reinterpret_cast<__half2*>(&r);
}
static __device__ __forceinline__ float wval(int i) {
    const float W[11] = {W0, W1, W2, W3, W4, W5, W4, W3, W2, W1, W0};
    float w = 0.f;
#pragma unroll
    for (int j = 0; j < 11; ++j) w = (i == WBASE + j) ? W[j] : w;
    return w;
}

__global__ __launch_bounds__(512, 6)
void ssim_tile(const float* __restrict__ img1, const float* __restrict__ img2,
               float* __restrict__ partials) {
    __shared__ _Float16 sWext[96];          // [WBASE..WBASE+10] = W[0..10]
    __shared__ _Float16 sIn[2 * INPLANE];   // 14,784 B : a | b
    __shared__ _Float16 sV[4 * VPLANE];     // 22,528 B : col-major, 44 rows
    __shared__ float wsum[8];

    const int tid  = threadIdx.x;
    const int lane = tid & 63;
    const int wv   = tid >> 6;
    const int lr = lane & 15;
    const int kc = lane >> 4;
    const int r0 = blockIdx.y * TH;
    const int c0 = blockIdx.x * TW;
    const bool fast = (blockIdx.x >= 1) & (blockIdx.x <= GX - 2) &
                      (blockIdx.y >= 1) & (blockIdx.y <= GY - 2);

    // prep item geometry (tid < 420)
    const int prow = (unsigned)tid / 10u;
    const int pch  = tid - prow * 10;
    const int pgr  = r0 - 5 + prow;
    const int pgc  = c0 - 8 + 8 * pch;
    const bool pok = (unsigned)pgr < IMGH && (unsigned)pgc < IMGW;
    const size_t goff = (size_t)pgr * IMGW + pgc;

    // per-tile image base (3 consecutive z-planes)
    const float* pa4[3];
    const float* pb4[3];
#pragma unroll
    for (int t = 0; t < 3; ++t) {
        const size_t pbase = ((size_t)blockIdx.z * 3 + t) * (IMGH * IMGW);
        pa4[t] = img1 + pbase;
        pb4[t] = img2 + pbase;
    }

    // aux: weight table + zero sV rows 42,43 (wave 7; prep threads are <420)
    if (tid >= 448) {
        const int t = tid - 448;
        sWext[t] = (_Float16)wval(t);
        if (t < 32) sWext[t + 64] = (_Float16)wval(t + 64);
#pragma unroll
        for (int j = 0; j < 4; ++j) {
            const int w = t + (j << 6);
            const int q = w >> 6, col = w & 63;
            *reinterpret_cast<unsigned*>(&sV[q * VPLANE + col * VSTRIDE + 42]) = 0u;
        }
    }

    f32x4 va1, va2, vb1, vb2;       // in-flight prep load registers
    const bool pipeline = fast && (tid < 420);

    // prologue: issue tile-0 loads
    if (pipeline) {
        const float* pa = pa4[0] + goff;
        const float* pb = pb4[0] + goff;
        asm volatile(
            "global_load_dwordx4 %0, %4, off\n\t"
            "global_load_dwordx4 %1, %4, off offset:16\n\t"
            "global_load_dwordx4 %2, %5, off\n\t"
            "global_load_dwordx4 %3, %5, off offset:16"
            : "=&v"(va1), "=&v"(va2), "=&v"(vb1), "=&v"(vb2)
            : "v"(pa), "v"(pb)
            : "memory");
    }

    half8v Wh, Av0, Av1;
    float lsum = 0.f;

#pragma unroll
    for (int t = 0; t < 3; ++t) {
        // ---- convert + store sIn(t) ----
        if (tid < 420) {
            if (pipeline) {
                asm volatile("s_waitcnt vmcnt(0)"
                             : "+v"(va1), "+v"(va2), "+v"(vb1), "+v"(vb2));
            } else {
                va1 = (f32x4){0.f, 0.f, 0.f, 0.f};
                va2 = vb1 = vb2 = va1;
                if (pok) {
                    const float* pa = pa4[t] + goff;
                    const float* pb = pb4[t] + goff;
                    va1 = *reinterpret_cast<const f32x4*>(pa);
                    va2 = *reinterpret_cast<const f32x4*>(pa + 4);
                    vb1 = *reinterpret_cast<const f32x4*>(pb);
                    vb2 = *reinterpret_cast<const f32x4*>(pb + 4);
                }
            }
            const int off = prow * INSTRIDE + 8 * pch;
            H8 ha, hb;
            ha.h2[0] = pkrtz(va1[0], va1[1]); ha.h2[1] = pkrtz(va1[2], va1[3]);
            ha.h2[2] = pkrtz(va2[0], va2[1]); ha.h2[3] = pkrtz(va2[2], va2[3]);
            hb.h2[0] = pkrtz(vb1[0], vb1[1]); hb.h2[1] = pkrtz(vb1[2], vb1[3]);
            hb.h2[2] = pkrtz(vb2[0], vb2[1]); hb.h2[3] = pkrtz(vb2[2], vb2[3]);
            *reinterpret_cast<float4*>(&sIn[off]) = ha.f4;
            *reinterpret_cast<float4*>(&sIn[INPLANE + off]) = hb.f4;
        }
        __syncthreads();                    // barrier A: sIn ready, v(t-1) done

        // issue loads for tile t+1 (fly under h+v of tile t)
        if (t < 2 && pipeline) {
            const float* pa = pa4[t + 1] + goff;
            const float* pb = pb4[t + 1] + goff;
            asm volatile(
                "global_load_dwordx4 %0, %4, off\n\t"
                "global_load_dwordx4 %1, %4, off offset:16\n\t"
                "global_load_dwordx4 %2, %5, off\n\t"
                "global_load_dwordx4 %3, %5, off offset:16"
                : "=&v"(va1), "=&v"(va2), "=&v"(vb1), "=&v"(vb2)
                : "v"(pa), "v"(pb)
                : "memory");
        }
        if (t == 0) {                       // weight fragments (sWext ready)
            const int bi = (kc << 3) - lr + WBASE;
#pragma unroll
            for (int e = 0; e < 8; ++e) Wh[e]  = sWext[bi - 3 + e];  // W[k-n-3]
#pragma unroll
            for (int e = 0; e < 8; ++e) Av0[e] = sWext[bi + e];      // W[k-m]
#pragma unroll
            for (int e = 0; e < 8; ++e) Av1[e] = sWext[bi - 4 + e];  // W[k-m-4]
        }

        // ---- h-phase: 24 half-positions (rt,ct,qp), 3 per wave ----
        {
            const int ct = (wv >> 1) & 3;
            const int qp = wv & 1;
#pragma unroll
            for (int rt = 0; rt < 3; ++rt) {
                const int rb = (rt == 0) ? 0 : (rt == 1 ? 16 : 26);
                const int base = (rb + lr) * INSTRIDE + 16 * ct + (kc << 3);
                H8 fa, fb;
                fa.f4 = *reinterpret_cast<const float4*>(&sIn[base]);
                fb.f4 = *reinterpret_cast<const float4*>(&sIn[INPLANE + base]);
                H8 f0, f1;
                if (qp == 0) {
                    f0 = fa; f1 = fb;
                } else {
#pragma unroll
                    for (int u = 0; u < 4; ++u) {
                        f0.h2[u] = __hfma2(fa.h2[u], fa.h2[u],
                                           __hmul2(fb.h2[u], fb.h2[u]));
                        f1.h2[u] = __hmul2(fa.h2[u], fb.h2[u]);
                    }
                }
                f32x4 d0 = {0.f, 0.f, 0.f, 0.f}, d1 = d0;
                d0 = __builtin_amdgcn_mfma_f32_16x16x32_f16(f0.v, Wh, d0, 0, 0, 0);
                d1 = __builtin_amdgcn_mfma_f32_16x16x32_f16(f1.v, Wh, d1, 0, 0, 0);
                const int p0 = qp * 2, p1 = qp * 2 + 1;
                const int vb = (16 * ct + lr) * VSTRIDE + rb + (kc << 2);
                uint2 s0, s1;
                __half2 h;
                h = pkrtz(d0[0], d0[1]); s0.x = *reinterpret_cast<unsigned*>(&h);
                h = pkrtz(d0[2], d0[3]); s0.y = *reinterpret_cast<unsigned*>(&h);
                h = pkrtz(d1[0], d1[1]); s1.x = *reinterpret_cast<unsigned*>(&h);
                h = pkrtz(d1[2], d1[3]); s1.y = *reinterpret_cast<unsigned*>(&h);
                if (rt < 2) {
                    *reinterpret_cast<uint2*>(&sV[p0 * VPLANE + vb]) = s0;
                    *reinterpret_cast<uint2*>(&sV[p1 * VPLANE + vb]) = s1;
                } else {   // rb=26: 4B-aligned only
                    unsigned* q0 = reinterpret_cast<unsigned*>(&sV[p0 * VPLANE + vb]);
                    unsigned* q1 = reinterpret_cast<unsigned*>(&sV[p1 * VPLANE + vb]);
                    q0[0] = s0.x; q0[1] = s0.y;
                    q1[0] = s1.x; q1[1] = s1.y;
                }
            }
        }
        __syncthreads();                    // barrier B: sV ready, sIn free

        // ---- v-phase: ct2 = wv&3, rt2 = wv>>2; 2xb64 reads; SSIM ----
        {
            const int ct2 = wv & 3;
            const int rt2 = wv >> 2;
            const int w0 = rt2 ? 12 : 0;
            const half8v Avx = rt2 ? Av1 : Av0;
            const int vbase = (16 * ct2 + lr) * VSTRIDE + w0 + (kc << 3);
            auto vread = [&](int q) -> half8v {
                const _Float16* p = &sV[q * VPLANE + vbase];
                H8 c;
                *reinterpret_cast<uint2*>(&c.u[0]) =
                    *reinterpret_cast<const uint2*>(p);
                *reinterpret_cast<uint2*>(&c.u[2]) =
                    *reinterpret_cast<const uint2*>(p + 4);
                return c.v;
            };
            f32x4 d0 = {0.f, 0.f, 0.f, 0.f}, d1 = d0, d2 = d0, d3 = d0;
            d0 = __builtin_amdgcn_mfma_f32_16x16x32_f16(Avx, vread(0), d0, 0, 0, 0);
            d1 = __builtin_amdgcn_mfma_f32_16x16x32_f16(Avx, vread(1), d1, 0, 0, 0);
            d2 = __builtin_amdgcn_mfma_f32_16x16x32_f16(Avx, vread(2), d2, 0, 0, 0);
            d3 = __builtin_amdgcn_mfma_f32_16x16x32_f16(Avx, vread(3), d3, 0, 0, 0);
#pragma unroll
            for (int r = 0; r < 4; ++r) {
                const float mu1 = d0[r], mu2 = d1[r], S = d2[r], eab = d3[r];
                const float mu11 = mu1 * mu1, mu22 = mu2 * mu2, mu12 = mu1 * mu2;
                const float s12 = eab - mu12;
                const float num = (2.f * mu12 + C1F) * (2.f * s12 + C2F);
                const float den = (mu11 + mu22 + C1F) * ((S - mu11 - mu22) + C2F);
                lsum += num * __builtin_amdgcn_rcpf(den);
            }
        }
    }

    // ---- deterministic block reduction (8 waves) ----
#pragma unroll
    for (int off = 32; off > 0; off >>= 1) lsum += __shfl_down(lsum, off, 64);
    if (lane == 0) wsum[wv] = lsum;
    __syncthreads();
    if (tid == 0) {
        float t = 0.f;
#pragma unroll
        for (int w = 0; w < 8; ++w) t += wsum[w];
        partials[((size_t)blockIdx.z * GY + blockIdx.y) * GX + blockIdx.x] = t;
    }
}

__global__ __launch_bounds__(1024)
void ssim_reduce(const float* __restrict__ partials, float* __restrict__ out, int n) {
    __shared__ float lds[1024];
    float s = 0.f;
    for (int i = threadIdx.x; i < n; i += 1024) s += partials[i];
    lds[threadIdx.x] = s;
    __syncthreads();
    for (int off = 512; off > 0; off >>= 1) {
        if ((int)threadIdx.x < off) lds[threadIdx.x] += lds[threadIdx.x + off];
        __syncthreads();
    }
    if (threadIdx.x == 0) out[0] = 1.f - lds[0] / (float)NPIX;
}

extern "C" void kernel_launch(void* const* d_in, const int* in_sizes, int n_in,
                              void* d_out, int out_size, void* d_ws, size_t ws_size,
                              hipStream_t stream) {
    const float* img1 = (const float*)d_in[0];
    const float* img2 = (const float*)d_in[1];
    float* out = (float*)d_out;
    float* partials = (float*)d_ws;

    dim3 grid(GX, GY, GZT);
    ssim_tile<<<grid, 512, 0, stream>>>(img1, img2, partials);
    ssim_reduce<<<1, 1024, 0, stream>>>(partials, out, NBLOCKS);
}